// Round 10
// baseline (1150.559 us; speedup 1.0000x reference)
//
#include <hip/hip_runtime.h>

// 8 independent LSTMs (HID=512, input=1 scalar/step) x T=256, batch 128, then a
// tiny (B,T)->(B,8) projection.
//
// Round 19: r17 base + 4-way split plain counters (ESCROW RETAINED).
//  r18 post-mortem (FAILED, by design): removing ONLY the sc1 escrow
//  reproduced r16's corruption (absmax 4.98e-2 ~ r16's 4.2e-2). PROVEN:
//  vmcnt store-ack = "accepted", NOT "L2-visible"; h lines vs counter line
//  ride different TCC channels; the escrow's ~700cyc MALL ack (drained by the
//  consumer's first wave-global WAITV(0)) is the load-bearing delay that keeps
//  detection slower than h-store settlement. All future sync keeps it.
//  This exonerates r16's split counters (bundled, never faulty).
//  r19 changes vs r17 (single sync-side variable):
//   - Plain publish adds go to cnt line [jt>>2] (4 lines/group, 64B apart):
//     4 parallel TCC RMW chains of 4 (~120cyc) instead of one chain of 16
//     (~500cyc). Poll: lanes 0-3 umax the 4 lines in one round,
//     __all(fv >= 4*(t+1)).
//   - sc1 escrow add (all 16 waves -> ONE MALL counter) + 256-spin
//     escalation to it: UNCHANGED. Masking delay identical to r17.
//  Everything else byte-identical to r17 (proven 1039us).

#define NBR   8
#define BATCH 128
#define HIDN  512
#define TLEN  256

typedef __attribute__((ext_vector_type(8))) short bf16x8;
typedef __attribute__((ext_vector_type(4))) float f32x4;

__device__ __forceinline__ unsigned short bf16_rne(float f) {
  unsigned int u = __float_as_uint(f);
  u += 0x7FFFu + ((u >> 16) & 1u);
  return (unsigned short)(u >> 16);
}

__device__ __forceinline__ float sigm(float x) {
  return __builtin_amdgcn_rcpf(1.0f + __expf(-x));
}
__device__ __forceinline__ float tanh_(float x) {
  float ax = fabsf(x);
  float e  = __expf(-2.0f * ax);
  float t  = (1.0f - e) * __builtin_amdgcn_rcpf(1.0f + e);
  return copysignf(t, x);
}

#define HLOADX(d, p, OFF, SC) \
  asm volatile("global_load_dwordx4 %0, %1, off offset:" OFF " " SC \
               : "=v"(d) : "v"(p))
#define DLOADX(d, p, SC) \
  asm volatile("global_load_dword %0, %1, off " SC : "=v"(d) : "v"(p))
#define DLOADF(d, p, SC) \
  asm volatile("global_load_dword %0, %1, off " SC : "=v"(d) : "v"(p))
#define QSTOREX(p, v, SC) \
  asm volatile("global_store_dwordx2 %0, %1, off " SC \
               :: "v"(p), "v"(v) : "memory")
#define QSTOREXO(p, v, OFF, SC) \
  asm volatile("global_store_dwordx2 %0, %1, off offset:" OFF " " SC \
               :: "v"(p), "v"(v) : "memory")
#define DSTOREX(p, v, SC) \
  asm volatile("global_store_dword %0, %1, off " SC \
               :: "v"(p), "v"(v) : "memory")
#define WAITV(N) asm volatile("s_waitcnt vmcnt(" #N ")" ::: "memory")
#define INVL1() asm volatile("buffer_inv sc0" ::: "memory")
#define SCHEDB() __builtin_amdgcn_sched_barrier(0)
// L2-executed atomics: cannot be served stale by L1. sc0 on the RET form is
// required (return-old); plain NR form executes at L2, sc1 form at MALL.
#define AADD_NR(p, v, SC) \
  asm volatile("global_atomic_add %0, %1, off " SC :: "v"(p), "v"(v) : "memory")
#define AUMAX_RET(d, p, v, SC) \
  asm volatile("global_atomic_umax %0, %1, %2, off " SC \
               : "=v"(d) : "v"(p), "v"(v) : "memory")

// 16 x 16B: row bb, bytes [q*16 + j*64], j = 0..15 (4 chunks of 4 ksteps).
#define LOAD_H(SC) do {                         \
    HLOADX(hvv[0][0], pc, "0",   SC);           \
    HLOADX(hvv[0][1], pc, "64",  SC);           \
    HLOADX(hvv[0][2], pc, "128", SC);           \
    HLOADX(hvv[0][3], pc, "192", SC);           \
    HLOADX(hvv[1][0], pc, "256", SC);           \
    HLOADX(hvv[1][1], pc, "320", SC);           \
    HLOADX(hvv[1][2], pc, "384", SC);           \
    HLOADX(hvv[1][3], pc, "448", SC);           \
    HLOADX(hvv[2][0], pc, "512", SC);           \
    HLOADX(hvv[2][1], pc, "576", SC);           \
    HLOADX(hvv[2][2], pc, "640", SC);           \
    HLOADX(hvv[2][3], pc, "704", SC);           \
    HLOADX(hvv[3][0], pc, "768", SC);           \
    HLOADX(hvv[3][1], pc, "832", SC);           \
    HLOADX(hvv[3][2], pc, "896", SC);           \
    HLOADX(hvv[3][3], pc, "960", SC);           \
  } while (0)

// 8 tiles tt = gate*2 + u (u = col-16-half); acc[tt] over K chunks. W from
// frag-major LDS: index tt*1024 + ks*64 + wb (wb = q*16+ln15) -> each read is
// 64 consecutive uint4 = conflict-free.
#define MFMA_CHUNK(C) do {                                                    \
    _Pragma("unroll")                                                         \
    for (int k4 = 0; k4 < 4; ++k4) {                                          \
      bf16x8 hfrag = __builtin_bit_cast(bf16x8, hvv[C][k4]);                  \
      _Pragma("unroll")                                                       \
      for (int tt = 0; tt < 8; ++tt) {                                        \
        bf16x8 wf = __builtin_bit_cast(bf16x8,                                \
            Wlds[tt * 1024 + (4 * (C) + k4) * 64 + wb]);                      \
        acc[tt] = __builtin_amdgcn_mfma_f32_16x16x32_bf16(                    \
            wf, hfrag, acc[tt], 0, 0, 0);                                     \
      }                                                                       \
    }                                                                         \
  } while (0)

// FM==1: pure (plain h exchange in local L2, 4-way split plain counters +
// sc1 escrow + escalation). FM==0: MALL protocol, per-wave flags.
#define STEP_LOOP(SC, FM)                                                     \
  for (int t = 0; t < TLEN; ++t) {                                            \
    f32x4 acc[8];                                                             \
    _Pragma("unroll")                                                         \
    for (int tt = 0; tt < 8; ++tt)                                            \
      acc[tt] = (f32x4){pb[tt * 4 + 0].y, pb[tt * 4 + 1].y,                   \
                        pb[tt * 4 + 2].y, pb[tt * 4 + 3].y};                  \
    const char* pc = curB + hoff;                                             \
    uint4 hvv[4][4];                                                          \
    float cv;                                                                 \
    DLOADF(cv, c_ptr + t, "");                                                \
    LOAD_H(SC);                                                               \
    WAITV(12); SCHEDB(); MFMA_CHUNK(0);                                       \
    WAITV(8);  SCHEDB(); MFMA_CHUNK(1);                                       \
    WAITV(4);  SCHEDB(); MFMA_CHUNK(2);                                       \
    WAITV(0);  SCHEDB(); MFMA_CHUNK(3);                                       \
    float hv3 = 0.f;                                                          \
    _Pragma("unroll")                                                         \
    for (int u = 0; u < 2; ++u) {                                             \
      unsigned lo = 0, hi = 0;                                                \
      _Pragma("unroll")                                                       \
      for (int r = 0; r < 4; ++r) {                                           \
        float gi = acc[0 + u][r] + pb[(0 + u) * 4 + r].x * cv;                \
        float gf = acc[2 + u][r] + pb[(2 + u) * 4 + r].x * cv;                \
        float gg = acc[4 + u][r] + pb[(4 + u) * 4 + r].x * cv;                \
        float go = acc[6 + u][r] + pb[(6 + u) * 4 + r].x * cv;                \
        float ncc = sigm(gf) * cc[u][r] + sigm(gi) * tanh_(gg);               \
        cc[u][r] = ncc;                                                       \
        float hval = sigm(go) * tanh_(ncc);                                   \
        unsigned hb = bf16_rne(hval);                                         \
        if (r == 0) lo = hb;                                                  \
        if (r == 1) lo |= hb << 16;                                           \
        if (r == 2) hi = hb;                                                  \
        if (r == 3) hi |= hb << 16;                                           \
        if (u == 1 && r == 3) hv3 = hval;                                     \
      }                                                                       \
      unsigned long long pack =                                               \
          (unsigned long long)lo | ((unsigned long long)hi << 32);            \
      QSTOREX(nxtB + (u ? soff1 : soff0), pack, SC);                          \
    }                                                                         \
    if (t == TLEN - 1) {                                                      \
      if (jt == 15 && q == 3)                                                 \
        ys[t * (NBR * BATCH) + n * BATCH + bb] = hv3;                         \
      break;                                                                  \
    }                                                                         \
    WAITV(0);                      /* my h stores acked */                    \
    const unsigned tgt = (unsigned)(t + 1);                                   \
    if (FM) {                                                                 \
      if (lane == 0) { AADD_NR(cntL, one, "");                                \
                       AADD_NR(cntM, one, "sc1"); }                           \
      INVL1();                     /* atomics bypass L1; no refill before h */\
      if (jt == 15 && q == 3)                                                 \
        ys[t * (NBR * BATCH) + n * BATCH + bb] = hv3;                         \
      const unsigned tgt4  = tgt << 2;                                        \
      const unsigned tgt16 = tgt << 4;                                        \
      int spins = 0;                                                          \
      for (;;) {                                                              \
        unsigned fv = 0xFFFFFFFFu;                                            \
        unsigned thr;                                                         \
        if (spins < 256) {                                                    \
          if (lane < 4) AUMAX_RET(fv, cntP, 0u, "sc0");                       \
          thr = tgt4;                                                         \
        } else {                                                              \
          if (lane < 4) AUMAX_RET(fv, cntM, 0u, "sc0 sc1");                   \
          thr = tgt16;                                                        \
        }                                                                     \
        WAITV(0); SCHEDB();        /* also drains the buffer_inv */           \
        if (__all((int)(fv >= thr))) break;                                   \
        ++spins; __builtin_amdgcn_s_sleep(1);                                 \
      }                                                                       \
    } else {                                                                  \
      if (jt == 15 && q == 3)                                                 \
        ys[t * (NBR * BATCH) + n * BATCH + bb] = hv3;                         \
      if (lane == 0) DSTOREX(myflag, tgt, "sc0 sc1");                         \
      for (;;) {                                                              \
        unsigned f0v;                                                         \
        DLOADX(f0v, pf0, "sc0 sc1");                                          \
        WAITV(0); SCHEDB();                                                   \
        if (__all((int)(f0v >= tgt))) break;                                  \
        __builtin_amdgcn_s_sleep(1);                                          \
      }                                                                       \
    }                                                                         \
    char* tsw = curB; curB = nxtB; nxtB = tsw;                                \
  }

__global__ __launch_bounds__(256, 1) void lstm_main(
    const float* __restrict__ c_in,   // (128,256)
    const float* __restrict__ Wih,    // (8,2048)
    const float* __restrict__ Whh,    // (8,2048,512)
    const float* __restrict__ b_ih,   // (8,2048)
    const float* __restrict__ b_hh,   // (8,2048)
    char* __restrict__ hImp,          // 2MB impure ping+pong, pre-zeroed ping
    char* __restrict__ hPure,         // 2MB: 8 XCD regions x (128KB ping + 128KB pong)
    float* __restrict__ ys,           // (256,8,128)
    unsigned int* __restrict__ iflags,// 8x128 impure per-wave flags, pre-zeroed
    unsigned int* __restrict__ pcnt,  // 8 XCD x 8 groups x 8 lines x 16 u32:
                                      //  lines 0-3 = split plain cnts, 4 = escrow
    unsigned int* __restrict__ vx,    // 256 tagged XCC slots, pre-zeroed
    unsigned int* __restrict__ vdict, // 8 verdicts, pre-zeroed
    unsigned int* __restrict__ ibar)  // 8x32 init-barrier slots, pre-zeroed
{
  // Frag-major W: slot = tile*1024 + ks*64 + q*16 + ln15  (tile = gate*2 + u).
  // Each ds_read_b128 (fixed tile,ks) touches 64 CONSECUTIVE uint4 slots.
  __shared__ uint4 Wlds[8192];  // 128KB
  __shared__ float2 Bp[128];    // {Wih, b_ih+b_hh} per slice gate-row

  const int tid  = threadIdx.x;
  const int lane = tid & 63;
  const int w    = tid >> 6;
  const int ln15 = lane & 15;
  const int q    = lane >> 4;
  const int q4   = q * 4;
  const int n    = blockIdx.x & 7;    // branch
  const int m    = blockIdx.x >> 3;   // 0..31
  const int jt   = m & 15;            // hidden-col tile (32 cols)
  const int bt   = m >> 4;            // batch half (64 rows)
  const int j0   = jt << 5;
  const int wb   = q * 16 + ln15;     // frag-major LDS read base (uint4)
  const unsigned one = 1u;

  unsigned xcc_raw;
  asm volatile("s_getreg_b32 %0, hwreg(HW_REG_XCC_ID)" : "=s"(xcc_raw));
  const unsigned xcc = xcc_raw & 0xFu;
  if (tid == 0) DSTOREX(&vx[blockIdx.x], 0xA5000000u | xcc, "sc0 sc1");

  // ---- stage Whh slice -> LDS bf16, frag-major, dest-linear (once) ----
  for (int idx = tid; idx < 8192; idx += 256) {
    int ln   = idx & 15;          // wcol within 16-col tile
    int q_   = (idx >> 4) & 3;    // k quarter (8 floats)
    int ks_  = (idx >> 6) & 15;   // kstep (32 floats)
    int tile = idx >> 10;         // 0..7 = gate*2 + u
    int g_   = tile >> 1;
    int uu   = tile & 1;
    const float* src = Whh +
        (size_t)(n * 2048 + g_ * 512 + j0 + uu * 16 + ln) * 512 + ks_ * 32 + q_ * 8;
    float4 f0 = *(const float4*)(src);
    float4 f1 = *(const float4*)(src + 4);
    uint4 v;
    v.x = (unsigned)bf16_rne(f0.x) | ((unsigned)bf16_rne(f0.y) << 16);
    v.y = (unsigned)bf16_rne(f0.z) | ((unsigned)bf16_rne(f0.w) << 16);
    v.z = (unsigned)bf16_rne(f1.x) | ((unsigned)bf16_rne(f1.y) << 16);
    v.w = (unsigned)bf16_rne(f1.z) | ((unsigned)bf16_rne(f1.w) << 16);
    Wlds[idx] = v;
  }
  if (tid < 128) {
    int g = n * 2048 + (tid >> 5) * 512 + j0 + (tid & 31);
    Bp[tid] = make_float2(Wih[g], b_ih[g] + b_hh[g]);
  }

  // ---- leader (m==0, wave 0): bounded purity check, publish verdict ----
  if (m == 0 && w == 0) {
    const unsigned ref = 0xA5000000u | xcc;
    unsigned v0 = 0, v1 = 0, v2 = 0, v3 = 0;
    int ok = 0;
    for (int it = 0; it < 16384; ++it) {
      DLOADX(v0, &vx[lane],       "sc0 sc1");
      DLOADX(v1, &vx[lane + 64],  "sc0 sc1");
      DLOADX(v2, &vx[lane + 128], "sc0 sc1");
      DLOADX(v3, &vx[lane + 192], "sc0 sc1");
      WAITV(0);
      if (__all((int)(((v0 & 0xFF000000u) == 0xA5000000u) &&
                      ((v1 & 0xFF000000u) == 0xA5000000u) &&
                      ((v2 & 0xFF000000u) == 0xA5000000u) &&
                      ((v3 & 0xFF000000u) == 0xA5000000u)))) { ok = 1; break; }
      __builtin_amdgcn_s_sleep(1);
    }
    unsigned verdict = 0;
    if (ok) {
      const bool mine = ((lane & 7) == n);
      int uni = __all((int)(!mine || (v0 == ref && v1 == ref && v2 == ref && v3 == ref)));
      int oth = __all((int)( mine || (v0 != ref && v1 != ref && v2 != ref && v3 != ref)));
      verdict = (uni && oth && (xcc < 8u)) ? 1u : 0u;
    }
    if (lane == 0)
      DSTOREX(&vdict[n], 0xB5000000u | (verdict << 8) | xcc, "sc0 sc1");
  }

  unsigned vd;
  for (;;) {
    DLOADX(vd, &vdict[n], "sc0 sc1");
    WAITV(0);
    if ((vd & 0xFF000000u) == 0xB5000000u) break;
    __builtin_amdgcn_s_sleep(2);
  }
  const int pure   = (int)((vd >> 8) & 1u);
  const unsigned x = vd & 0xFu;

  const int bb = bt * 64 + w * 16 + ln15;       // my batch row
  const size_t hoff  = (size_t)bb * 1024 + (size_t)q * 16;
  const size_t soff0 = (size_t)bb * 1024 + (size_t)(j0 + q4) * 2;
  const size_t soff1 = soff0 + 32;              // +16 cols
  const float* c_ptr = c_in + (size_t)bb * 256;

  float cc[2][4];
#pragma unroll
  for (int u = 0; u < 2; ++u)
#pragma unroll
    for (int r = 0; r < 4; ++r) cc[u][r] = 0.0f;

  // Sync group: 16 waves sharing (bt,w) across jt=0..15 — closed set.
  // Group id within XCD: gidx = bt*4 + w (8 groups). 8 lines (512B) each:
  // lines 0-3 split plain counters (by jt>>2), line 4 = MALL escrow counter.
  const int gidx = bt * 4 + w;
  char *curB, *nxtB;
  unsigned int *myflag, *cntL, *cntM, *cntS;
  const unsigned int *cntP, *pf0;
  if (pure) {
    curB = hPure + (size_t)x * 262144; nxtB = curB + 131072;
    cntS = pcnt + x * 1024 + gidx * 128;        // group base (8 x 64B lines)
    cntL = cntS + (jt >> 2) * 16;               // my split plain-counter line
    cntP = cntS + (lane & 3) * 16;              // lanes 0-3 poll the 4 lines
    cntM = cntS + 64;                           // escrow line (line 4)
    myflag = cntS;                               // unused
    pf0    = cntS;                               // unused
  } else {
    curB = hImp + (size_t)n * 131072; nxtB = curB + (size_t)NBR * 131072;
    unsigned int* flagB = iflags + n * 128;
    myflag = flagB + m * 4 + w;                  // per-wave flag
    pf0    = flagB + bt * 64 + lane;             // 64 same-batch-half wave flags
    cntS = myflag; cntL = myflag; cntM = myflag; cntP = myflag;  // unused
  }

  __syncthreads();   // Wlds + Bp ready; every wave has the verdict

  // Hoist {Wih, bias} for my 32 output elems into registers (loop-invariant).
  float2 pb[32];
#pragma unroll
  for (int g_ = 0; g_ < 4; ++g_)
#pragma unroll
    for (int uu = 0; uu < 2; ++uu)
#pragma unroll
      for (int r = 0; r < 4; ++r)
        pb[(g_ * 2 + uu) * 4 + r] = Bp[g_ * 32 + uu * 16 + q4 + r];

  if (pure) {
    // scrub my 1/32 of region[x] to 0 (stale dirty lines live only in THIS L2)
    char* rp = hPure + (size_t)x * 262144 + (size_t)m * 8192;
    for (int i = tid; i < 1024; i += 256)
      QSTOREXO(rp + (size_t)i * 8, 0ull, "0", "sc0");
    // jt==0 blocks scrub their group's 5 counter lines: L2 dirty-0 first,
    // then write-through to MALL (eviction/refill then always lands on 0).
    if (jt == 0 && lane == 0) {
      DSTOREX(cntS,      0u, "sc0");
      DSTOREX(cntS + 16, 0u, "sc0");
      DSTOREX(cntS + 32, 0u, "sc0");
      DSTOREX(cntS + 48, 0u, "sc0");
      DSTOREX(cntS + 64, 0u, "sc0");
      WAITV(0);
      DSTOREX(cntS,      0u, "sc0 sc1");
      DSTOREX(cntS + 16, 0u, "sc0 sc1");
      DSTOREX(cntS + 32, 0u, "sc0 sc1");
      DSTOREX(cntS + 48, 0u, "sc0 sc1");
      DSTOREX(cntS + 64, 0u, "sc0 sc1");
    }
    WAITV(0);
    __syncthreads();
    if (tid == 0) DSTOREX(&ibar[x * 32 + m], 1u, "sc0 sc1");
    for (;;) {
      unsigned iv;
      DLOADX(iv, &ibar[x * 32 + (lane & 31)], "sc0 sc1");
      WAITV(0);
      if (__all((int)(iv >= 1u))) break;
      __builtin_amdgcn_s_sleep(2);
    }
    INVL1(); WAITV(0);
    STEP_LOOP("", 1)
  } else {
    STEP_LOOP("sc0 sc1", 0)
  }
}

// out[b,j] = sum_t (sum_n ys[t,n,b] * x[n,b,t]) * Wl[j,t] + bl[j]
__global__ __launch_bounds__(256) void finalize_k(
    const float* __restrict__ ys, const float* __restrict__ x,
    const float* __restrict__ Wl, const float* __restrict__ bl,
    float* __restrict__ out)
{
  int b = blockIdx.x;
  int tid = threadIdx.x;  // = t
  __shared__ float r[256];
  float acc = 0.f;
#pragma unroll
  for (int n = 0; n < NBR; ++n)
    acc += ys[tid * (NBR * BATCH) + n * BATCH + b] * x[(n * BATCH + b) * 256 + tid];
  r[tid] = acc;
  __syncthreads();
  int wv = tid >> 6, ln = tid & 63;
#pragma unroll
  for (int jj = 0; jj < 2; ++jj) {
    int j = wv * 2 + jj;
    float p = 0.f;
#pragma unroll
    for (int t2 = ln; t2 < 256; t2 += 64) p += r[t2] * Wl[j * 256 + t2];
#pragma unroll
    for (int s = 32; s > 0; s >>= 1) p += __shfl_down(p, s, 64);
    if (ln == 0) out[b * NBR + j] = p + bl[j];
  }
}

extern "C" void kernel_launch(void* const* d_in, const int* in_sizes, int n_in,
                              void* d_out, int out_size, void* d_ws, size_t ws_size,
                              hipStream_t stream) {
  const float* x    = (const float*)d_in[0];
  const float* c    = (const float*)d_in[1];
  const float* Wih  = (const float*)d_in[2];
  const float* Whh  = (const float*)d_in[3];
  const float* b_ih = (const float*)d_in[4];
  const float* b_hh = (const float*)d_in[5];
  // d_in[6] = hn0 (zeros; impure ping memset, pure regions scrubbed in-kernel)
  const float* Wl   = (const float*)d_in[7];
  const float* bl   = (const float*)d_in[8];
  float* out = (float*)d_out;

  char* ws = (char*)d_ws;
  char*  hImp  = ws;                                   // 2MB
  char*  hPure = ws + (2u << 20);                      // 2MB (8 x 256KB, XCD-indexed)
  float* ys    = (float*)(ws + (4u << 20));            // 1MB
  unsigned int* ctrl   = (unsigned int*)(ws + (5u << 20));
  unsigned int* iflags = ctrl;                         // 1024 u32
  unsigned int* pcnt   = ctrl + 1024;                  // 8192 u32 (8 x 8 x 8 x 16)
  unsigned int* vx     = ctrl + 9216;                  // 256 u32
  unsigned int* vdict  = ctrl + 9472;                  // 8 u32
  unsigned int* ibar   = ctrl + 9480;                  // 256 u32

  // ws re-poisoned (0xAA) before every timed launch: re-init every call.
  (void)hipMemsetAsync(hImp, 0, 1u << 20, stream);     // impure h(t=0) = 0
  (void)hipMemsetAsync(ctrl, 0, 9736u * sizeof(unsigned int), stream);

  lstm_main<<<256, 256, 0, stream>>>(c, Wih, Whh, b_ih, b_hh, hImp, hPure, ys,
                                     iflags, pcnt, vx, vdict, ibar);
  finalize_k<<<BATCH, 256, 0, stream>>>(ys, x, Wl, bl, out);
}